// Round 11
// baseline (2801.793 us; speedup 1.0000x reference)
//
#include <hip/hip_runtime.h>
#include <hip/hip_bf16.h>

// CTRNN: T=512, B=64, I=512, H=1024 — single persistent kernel, 64 blocks x 512 thr.
// Waves 0-3 ("consumers"): EXACT round-8 recurrence protocol (proven, 2.64us/step):
//   poll 4 producers' flags -> sc0sc1 A-loads -> 32 whh MFMAs -> Pr write -> barrier A
//   -> reduce + xp(LDS) + bias + sigmoid -> ring store -> vmcnt(0) -> barrier B
//   -> flag -> out store.
// Waves 4-7 ("xp producers"): compute this block's xp tile for step t+2 into a
//   3-deep LDS ring (16x64 f32). n-split per wave (16 cols, full K=512), W_in
//   fragments pinned in 64 VGPRs/lane. Same 2 barriers per iteration.
// xp slot (t+2)%3 written before barrier A of iter t; read at iter t+2 between
// A and B; (t+2)%3 != t%3 and read < B_t < next write  => race-free by barriers.

typedef __attribute__((ext_vector_type(8))) short short8;
typedef __attribute__((ext_vector_type(4))) float f32x4;
typedef unsigned long long ull;

#define TT 512
#define BB 64
#define II 512
#define HH 1024

__device__ __forceinline__ short f2bf(float f) {
  unsigned u = __builtin_bit_cast(unsigned, f);
  u += 0x7fffu + ((u >> 16) & 1u);   // RNE
  return (short)(u >> 16);
}

__device__ __forceinline__ short8 pack8(const float* p) {
  short8 s;
  s[0] = f2bf(p[0]); s[1] = f2bf(p[1]); s[2] = f2bf(p[2]); s[3] = f2bf(p[3]);
  s[4] = f2bf(p[4]); s[5] = f2bf(p[5]); s[6] = f2bf(p[6]); s[7] = f2bf(p[7]);
  return s;
}

__global__ __launch_bounds__(512, 1) void rnn_persist(
    const float* __restrict__ x, const float* __restrict__ h0,
    const float* __restrict__ Win, const float* __restrict__ bin,
    const float* __restrict__ Whh, const float* __restrict__ bhh,
    float* __restrict__ out, short* __restrict__ ring0,
    short* __restrict__ ring1, int* __restrict__ flags) {
  __shared__ short Wl[64 * 1024];    // W_hh frag (kc,n) at (kc*64+n)*8 shorts, 128 KB
  __shared__ float Pr[4 * 16 * 68];  // consumer K-partials, stride 68, 17 KB
  __shared__ float Xp[3][16 * 68];   // xp ring, 3 slots x 16 rows x 68 stride, 12.75 KB

  const int bid = blockIdx.x;
  const int r = bid & 3, g = bid >> 2;
  const int tid = threadIdx.x;
  const bool cons = (tid < 256);
  const int l = tid & 63;
  const int lr = l & 15, lg = l >> 4;
  const int n0 = g * 64;

  // ================= PROLOGUE =================
  // consumer-side persistent state
  f32x4 hpv, bias;
  size_t oidx = 0, ringoff = 0;
  int fidx = 0;
  const short* bW = nullptr;
  size_t abase = 0;
  int brow = 0, c0 = 0;

  // producer-side persistent state
  short8 wf[16];
  int pw = 0;

  if (cons) {
    const int w = tid >> 6;
    // stage W_hh rows [64g,64g+64), K-major bf16 fragments (256 threads)
    for (int j = 0; j < 32; ++j) {
      int c = j * 256 + tid;           // c = n*128 + kc
      int kc = c & 127, n = c >> 7;
      const float* src = Whh + (size_t)(n0 + n) * HH + kc * 8;
      float4 v0 = *(const float4*)src;
      float4 v1 = *(const float4*)(src + 4);
      short* d = Wl + (((size_t)kc * 64 + n) << 3);
      d[0] = f2bf(v0.x); d[1] = f2bf(v0.y); d[2] = f2bf(v0.z); d[3] = f2bf(v0.w);
      d[4] = f2bf(v1.x); d[5] = f2bf(v1.y); d[6] = f2bf(v1.z); d[7] = f2bf(v1.w);
    }
    brow = tid >> 4;
    c0 = (tid & 15) * 4;
    oidx = (size_t)(16 * r + brow) * HH + n0 + c0;
    ringoff = (((size_t)(r * 128 + 8 * g + (c0 >> 3)) * 16 + brow) << 3) + (c0 & 7);
    #pragma unroll
    for (int k = 0; k < 4; ++k)
      bias[k] = bin[n0 + c0 + k] + bhh[n0 + c0 + k];
    // init ring0 from h0; carry own h in register
    {
      float4 v = *(const float4*)(h0 + oidx);
      hpv[0] = v.x; hpv[1] = v.y; hpv[2] = v.z; hpv[3] = v.w;
      ull u = (ull)(unsigned short)f2bf(v.x)
            | ((ull)(unsigned short)f2bf(v.y) << 16)
            | ((ull)(unsigned short)f2bf(v.z) << 32)
            | ((ull)(unsigned short)f2bf(v.w) << 48);
      __hip_atomic_store((ull*)(ring0 + ringoff), u,
                         __ATOMIC_RELAXED, __HIP_MEMORY_SCOPE_AGENT);
    }
    fidx = 16 * w + 4 * (l & 3) + r;
    bW = Wl + ((((size_t)(32 * w + lg)) * 64 + lr) << 3);
    abase = ((((size_t)(r * 128 + 32 * w + lg)) * 16 + lr) << 3);
  } else {
    pw = (tid >> 6) & 3;  // producer wave 0..3, owns cols [16pw, 16pw+16)
    // pin W_in fragments: col = n0+16pw+lr, k = kidx*32 + lg*8
    #pragma unroll
    for (int kidx = 0; kidx < 16; ++kidx) {
      const float* src = Win + (size_t)(n0 + 16 * pw + lr) * II + kidx * 32 + lg * 8;
      float tmp[8];
      *(float4*)&tmp[0] = *(const float4*)src;
      *(float4*)&tmp[4] = *(const float4*)(src + 4);
      wf[kidx] = pack8(tmp);
    }
    // precompute xp[0] -> slot 0, xp[1] -> slot 1
    #pragma unroll
    for (int t0 = 0; t0 < 2; ++t0) {
      const float* xq = x + ((size_t)t0 * BB + 16 * r + lr) * II + lg * 8;
      f32x4 pacc = (f32x4){0.f, 0.f, 0.f, 0.f};
      #pragma unroll
      for (int kidx = 0; kidx < 16; ++kidx) {
        float tmp[8];
        *(float4*)&tmp[0] = *(const float4*)(xq + kidx * 32);
        *(float4*)&tmp[4] = *(const float4*)(xq + kidx * 32 + 4);
        pacc = __builtin_amdgcn_mfma_f32_16x16x32_bf16(pack8(tmp), wf[kidx], pacc, 0, 0, 0);
      }
      #pragma unroll
      for (int j = 0; j < 4; ++j)
        Xp[t0][(lg * 4 + j) * 68 + 16 * pw + lr] = pacc[j];
    }
  }

  __syncthreads();  // W_hh + xp[0..1] staged; consumer ring-init vmcnt drained
  if (tid == 0)
    __hip_atomic_store(&flags[bid], 1, __ATOMIC_RELAXED, __HIP_MEMORY_SCOPE_AGENT);

  // ================= MAIN LOOP =================
  for (int t = 0; t < TT; ++t) {
    f32x4 acc[4];
    if (cons) {
      short* rc = (t & 1) ? ring1 : ring0;
      // 1. wait for this wave's 4 producers to have published h_t
      {
        int target = t + 1;
        while (!__all(__hip_atomic_load(&flags[fidx], __ATOMIC_RELAXED,
                                        __HIP_MEMORY_SCOPE_AGENT) >= target))
          __builtin_amdgcn_s_sleep(1);
      }
      // 2. coherent A loads of this wave's K-slice
      const short* ar = rc + abase;
      const short* ar2 = ar + 2048;  // +4096 bytes
      int4 fa[8];
#define LDA(I, BASE, OFF) \
      asm volatile("global_load_dwordx4 %0, %1, off offset:%2 sc0 sc1" \
                   : "=v"(fa[I]) : "v"(BASE), "n"(OFF))
      LDA(0, ar, 0); LDA(1, ar, 1024); LDA(2, ar, 2048); LDA(3, ar, 3072);
      LDA(4, ar2, 0); LDA(5, ar2, 1024); LDA(6, ar2, 2048); LDA(7, ar2, 3072);
#undef LDA
      asm volatile("s_waitcnt vmcnt(0)" ::: "memory");
      __builtin_amdgcn_sched_barrier(0);
      // 3. whh MFMAs
      acc[0] = acc[1] = acc[2] = acc[3] = (f32x4){0.f, 0.f, 0.f, 0.f};
      #pragma unroll
      for (int i = 0; i < 8; ++i) {
        short8 a = __builtin_bit_cast(short8, fa[i]);
        acc[0] = __builtin_amdgcn_mfma_f32_16x16x32_bf16(
            a, *(const short8*)(bW + i * 2048 + 0),   acc[0], 0, 0, 0);
        acc[1] = __builtin_amdgcn_mfma_f32_16x16x32_bf16(
            a, *(const short8*)(bW + i * 2048 + 128), acc[1], 0, 0, 0);
        acc[2] = __builtin_amdgcn_mfma_f32_16x16x32_bf16(
            a, *(const short8*)(bW + i * 2048 + 256), acc[2], 0, 0, 0);
        acc[3] = __builtin_amdgcn_mfma_f32_16x16x32_bf16(
            a, *(const short8*)(bW + i * 2048 + 384), acc[3], 0, 0, 0);
      }
      // 4. publish K-partials
      {
        const int w = tid >> 6;
        float* pwr = Pr + w * 1088;
        #pragma unroll
        for (int nt = 0; nt < 4; ++nt) {
          #pragma unroll
          for (int jj = 0; jj < 4; ++jj)
            pwr[(lg * 4 + jj) * 68 + nt * 16 + lr] = acc[nt][jj];
        }
      }
    } else {
      // producers: compute xp[t+2] -> slot (t+2)%3
      if (t + 2 < TT) {
        const int wslot = (t + 2) % 3;
        const float* xq = x + ((size_t)(t + 2) * BB + 16 * r + lr) * II + lg * 8;
        f32x4 pacc = (f32x4){0.f, 0.f, 0.f, 0.f};
        #pragma unroll
        for (int kidx = 0; kidx < 16; ++kidx) {
          float tmp[8];
          *(float4*)&tmp[0] = *(const float4*)(xq + kidx * 32);
          *(float4*)&tmp[4] = *(const float4*)(xq + kidx * 32 + 4);
          pacc = __builtin_amdgcn_mfma_f32_16x16x32_bf16(pack8(tmp), wf[kidx], pacc, 0, 0, 0);
        }
        #pragma unroll
        for (int j = 0; j < 4; ++j)
          Xp[wslot][(lg * 4 + j) * 68 + 16 * pw + lr] = pacc[j];
      }
    }

    __syncthreads();  // barrier A: Pr + xp slot ordering

    f32x4 hn;
    if (cons) {
      short* rn = (t & 1) ? ring0 : ring1;
      // 5. reduce 4 K-partials + xp(LDS) + bias + sigmoid
      const float* pb = Pr + brow * 68 + c0;
      const float* xpb = &Xp[t % 3][brow * 68 + c0];
      f32x4 s = *(const f32x4*)(pb)
              + *(const f32x4*)(pb + 1088)
              + *(const f32x4*)(pb + 2176)
              + *(const f32x4*)(pb + 3264)
              + *(const f32x4*)(xpb);
      #pragma unroll
      for (int k = 0; k < 4; ++k) {
        float pre = s[k] + bias[k];
        float sg = 1.f / (1.f + __expf(-pre));
        hn[k] = 0.8f * hpv[k] + 0.2f * sg;  // 1-ALPHA, ALPHA, GAIN=1
      }
      // 6. publish h_{t+1} to ring
      ull u = (ull)(unsigned short)f2bf(hn[0])
            | ((ull)(unsigned short)f2bf(hn[1]) << 16)
            | ((ull)(unsigned short)f2bf(hn[2]) << 32)
            | ((ull)(unsigned short)f2bf(hn[3]) << 48);
      __hip_atomic_store((ull*)(rn + ringoff), u,
                         __ATOMIC_RELAXED, __HIP_MEMORY_SCOPE_AGENT);
      // 7. drain ring stores
      asm volatile("s_waitcnt vmcnt(0)" ::: "memory");
    }

    __syncthreads();  // barrier B: all consumer ring stores drained; Pr reuse guard

    if (tid == 0)
      __hip_atomic_store(&flags[bid], t + 2, __ATOMIC_RELAXED, __HIP_MEMORY_SCOPE_AGENT);

    if (cons) {
      // 8. non-critical tail
      float* outt = out + (size_t)t * (BB * HH);
      *(float4*)(outt + oidx) = *(float4*)&hn;
      if (t == TT - 1)
        *(float4*)(out + (size_t)TT * BB * HH + oidx) = *(float4*)&hn;
      hpv = hn;
    }
  }
}

extern "C" void kernel_launch(void* const* d_in, const int* in_sizes, int n_in,
                              void* d_out, int out_size, void* d_ws, size_t ws_size,
                              hipStream_t stream) {
  const float* x   = (const float*)d_in[0];
  const float* h0  = (const float*)d_in[1];
  const float* Win = (const float*)d_in[2];
  const float* bin = (const float*)d_in[3];
  const float* Whh = (const float*)d_in[4];
  const float* bhh = (const float*)d_in[5];
  float* out = (float*)d_out;

  int* flags = (int*)d_ws;                       // 64 ints (256 B)
  short* ring0 = (short*)((char*)d_ws + 256);    // 128 KB
  short* ring1 = ring0 + BB * HH;                // 128 KB (total 262,400 B, proven)

  hipMemsetAsync(d_ws, 0, 256, stream);
  rnn_persist<<<dim3(64), 512, 0, stream>>>(x, h0, Win, bin, Whh, bhh,
                                            out, ring0, ring1, flags);
}

// Round 15
// 1655.252 us; speedup vs baseline: 1.6927x; 1.6927x over previous
//
#include <hip/hip_runtime.h>
#include <hip/hip_bf16.h>

// CTRNN: T=512, B=64, I=512, H=1024 — two dispatches (proven structure).
//   1) xproj (rewritten): 512 blocks, one per timestep t. x[t] staged once into
//      LDS as MFMA A-frags (64 KB, single barrier); then 16 n-groups with
//      PER-WAVE-PRIVATE Win staging (16 cols/wave, 16 KB region, no barriers,
//      no cross-wave reduction; full K=512 per wave). out[t] = xp + b_in + b_hh.
//   2) rnn_persist: BYTE-IDENTICAL to round 8 (proven 2.64us/step, absmax 3.9e-3):
//      64 blocks = 4 batch-groups x 16 col-groups; W_hh in LDS; waves K-split;
//      LDS reduce; bf16 h-ring in d_ws + per-block flags
//      (publish -> vmcnt(0) -> barrier -> flag); own-h in registers; xp prefetched
//      from out in the non-critical tail (plain loads — inter-kernel ordering).

typedef __attribute__((ext_vector_type(8))) short short8;
typedef __attribute__((ext_vector_type(4))) float f32x4;
typedef unsigned long long ull;

#define TT 512
#define BB 64
#define II 512
#define HH 1024

__device__ __forceinline__ short f2bf(float f) {
  unsigned u = __builtin_bit_cast(unsigned, f);
  u += 0x7fffu + ((u >> 16) & 1u);   // RNE
  return (short)(u >> 16);
}

// ---------------- xproj: 512 blocks x 256 thr; block = one timestep (64 rows)
__global__ __launch_bounds__(256) void xproj_kernel(
    const float* __restrict__ x, const float* __restrict__ Win,
    const float* __restrict__ bin, const float* __restrict__ bhh,
    float* __restrict__ out) {
  __shared__ short xL[64 * 512];      // A-frags: (((kc6)*4+mt)*16+row)*8 + k7, 64 KB
  __shared__ short wL[4][16 * 512];   // per-wave B-frags: ((kc6*16)+n16)*8, 16 KB each

  const int tid = threadIdx.x;
  const int l = tid & 63, w = tid >> 6;
  const int lr = l & 15, lg = l >> 4;
  const int t = blockIdx.x;

  // ---- stage x[t] (64 rows x 512 k f32) -> bf16 A-frags, fully coalesced
  {
    const float* xt = x + (size_t)t * (BB * II);
    #pragma unroll 4
    for (int it = 0; it < 32; ++it) {
      int idx = it * 256 + tid;          // float4 units, 8192 total
      int row = idx >> 7;                // 128 float4 per row
      int k4 = idx & 127;
      float4 v = *(const float4*)(xt + (size_t)row * II + k4 * 4);
      short* d = xL + (((size_t)(k4 >> 1) * 4 + (row >> 4)) * 16 + (row & 15)) * 8
                    + (k4 & 1) * 4;
      d[0] = f2bf(v.x); d[1] = f2bf(v.y); d[2] = f2bf(v.z); d[3] = f2bf(v.w);
    }
  }
  __syncthreads();  // the only barrier: x-frags visible to all waves

  float* outt = out + (size_t)t * (BB * HH);

  for (int ng = 0; ng < 16; ++ng) {
    // ---- per-wave Win staging: cols [64ng+16w, +16), 16x512 f32, coalesced
    const float* ws = Win + (size_t)(ng * 64 + w * 16) * II;
    short* mywL = wL[w];
    #pragma unroll 4
    for (int it = 0; it < 32; ++it) {
      int idx = it * 64 + l;             // float4 units, 2048 total
      int row = idx >> 7;                // out-col within the 16
      int k4 = idx & 127;
      float4 v = *(const float4*)(ws + (size_t)row * II + k4 * 4);
      short* d = mywL + (((size_t)(k4 >> 1) * 16 + row) * 8 + (k4 & 1) * 4);
      d[0] = f2bf(v.x); d[1] = f2bf(v.y); d[2] = f2bf(v.z); d[3] = f2bf(v.w);
    }
    // (same-wave LDS dependency: compiler inserts lgkmcnt before ds_reads)

    // ---- 64 MFMAs: 4 m-tiles x 16 k-windows, B col = lr, full K = 512
    f32x4 acc[4];
    acc[0] = acc[1] = acc[2] = acc[3] = (f32x4){0.f, 0.f, 0.f, 0.f};
    #pragma unroll
    for (int kc = 0; kc < 16; ++kc) {
      int kc6 = kc * 4 + lg;
      short8 b = *(const short8*)(mywL + ((size_t)kc6 * 16 + lr) * 8);
      acc[0] = __builtin_amdgcn_mfma_f32_16x16x32_bf16(
          *(const short8*)(xL + (((size_t)kc6 * 4 + 0) * 16 + lr) * 8), b, acc[0], 0, 0, 0);
      acc[1] = __builtin_amdgcn_mfma_f32_16x16x32_bf16(
          *(const short8*)(xL + (((size_t)kc6 * 4 + 1) * 16 + lr) * 8), b, acc[1], 0, 0, 0);
      acc[2] = __builtin_amdgcn_mfma_f32_16x16x32_bf16(
          *(const short8*)(xL + (((size_t)kc6 * 4 + 2) * 16 + lr) * 8), b, acc[2], 0, 0, 0);
      acc[3] = __builtin_amdgcn_mfma_f32_16x16x32_bf16(
          *(const short8*)(xL + (((size_t)kc6 * 4 + 3) * 16 + lr) * 8), b, acc[3], 0, 0, 0);
    }

    // ---- epilogue: col n fixed per lane; rows mt*16 + lg*4 + j
    int n = ng * 64 + w * 16 + lr;
    float bb = bin[n] + bhh[n];
    #pragma unroll
    for (int mt = 0; mt < 4; ++mt) {
      #pragma unroll
      for (int j = 0; j < 4; ++j)
        outt[(size_t)(mt * 16 + lg * 4 + j) * HH + n] = acc[mt][j] + bb;
    }
  }
}

// ---------------- persistent recurrence: BYTE-IDENTICAL to round 8 (proven)
__global__ __launch_bounds__(256) void rnn_persist(
    const float* __restrict__ h0, const float* __restrict__ Whh,
    float* __restrict__ out, short* __restrict__ ring0,
    short* __restrict__ ring1, int* __restrict__ flags) {
  __shared__ short Wl[64 * 1024];   // fragment (kc,n) at (kc*64+n)*8 shorts, 128 KB
  __shared__ float Pr[4 * 16 * 68]; // per-wave K-partials, stride 68 (anti-conflict)

  const int bid = blockIdx.x;
  const int r = bid & 3, g = bid >> 2;
  const int tid = threadIdx.x;
  const int l = tid & 63, w = tid >> 6;
  const int lr = l & 15, lg = l >> 4;

  // stage W_hh rows (output cols) [64g, 64g+64), K-major bf16 fragments
  const int n0 = g * 64;
  for (int j = 0; j < 32; ++j) {
    int c = j * 256 + tid;           // c = n*128 + kc
    int kc = c & 127, n = c >> 7;
    const float* src = Whh + (size_t)(n0 + n) * HH + kc * 8;
    float4 v0 = *(const float4*)src;
    float4 v1 = *(const float4*)(src + 4);
    short* d = Wl + (((size_t)kc * 64 + n) << 3);
    d[0] = f2bf(v0.x); d[1] = f2bf(v0.y); d[2] = f2bf(v0.z); d[3] = f2bf(v0.w);
    d[4] = f2bf(v1.x); d[5] = f2bf(v1.y); d[6] = f2bf(v1.z); d[7] = f2bf(v1.w);
  }

  // epilogue thread tile: row brow (0..15), cols c0..c0+3 within block chunk
  const int brow = tid >> 4;
  const int c0 = (tid & 15) * 4;
  const size_t oidx = (size_t)(16 * r + brow) * HH + n0 + c0;
  const size_t ringoff =
      (((size_t)(r * 128 + 8 * g + (c0 >> 3)) * 16 + brow) << 3) + (c0 & 7);

  // init ring0 from h0; carry own h in register
  f32x4 hpv;
  {
    float4 v = *(const float4*)(h0 + oidx);
    hpv[0] = v.x; hpv[1] = v.y; hpv[2] = v.z; hpv[3] = v.w;
    ull u = (ull)(unsigned short)f2bf(v.x)
          | ((ull)(unsigned short)f2bf(v.y) << 16)
          | ((ull)(unsigned short)f2bf(v.z) << 32)
          | ((ull)(unsigned short)f2bf(v.w) << 48);
    __hip_atomic_store((ull*)(ring0 + ringoff), u,
                       __ATOMIC_RELAXED, __HIP_MEMORY_SCOPE_AGENT);
  }
  // prefetch x_proj[0] (plain load)
  f32x4 xpv;
  {
    float4 v = *(const float4*)(out + oidx);
    xpv[0] = v.x; xpv[1] = v.y; xpv[2] = v.z; xpv[3] = v.w;
  }
  __syncthreads();  // drains vmcnt: init ring stores at coherence point
  if (tid == 0)
    __hip_atomic_store(&flags[bid], 1, __ATOMIC_RELAXED, __HIP_MEMORY_SCOPE_AGENT);

  // wave w consumes kc in [32w, 32w+32) -> producer blocks bid' = 16w + 4(l&3) + r
  const int fidx = 16 * w + 4 * (l & 3) + r;
  const short* bW = Wl + ((((size_t)(32 * w + lg)) * 64 + lr) << 3);
  const size_t abase = ((((size_t)(r * 128 + 32 * w + lg)) * 16 + lr) << 3);

  for (int t = 0; t < TT; ++t) {
    short* rc = (t & 1) ? ring1 : ring0;
    short* rn = (t & 1) ? ring0 : ring1;
    float* outt = out + (size_t)t * (BB * HH);

    // 1. wait for this wave's 4 producers to have published h_t
    {
      int target = t + 1;
      while (!__all(__hip_atomic_load(&flags[fidx], __ATOMIC_RELAXED,
                                      __HIP_MEMORY_SCOPE_AGENT) >= target))
        __builtin_amdgcn_s_sleep(1);
    }

    // 2. coherent A loads of this wave's K-slice (kc = 32w+lg+4i)
    const short* ar = rc + abase;
    const short* ar2 = ar + 2048;  // +4096 bytes
    int4 fa[8];
#define LDA(I, BASE, OFF) \
    asm volatile("global_load_dwordx4 %0, %1, off offset:%2 sc0 sc1" \
                 : "=v"(fa[I]) : "v"(BASE), "n"(OFF))
    LDA(0, ar, 0); LDA(1, ar, 1024); LDA(2, ar, 2048); LDA(3, ar, 3072);
    LDA(4, ar2, 0); LDA(5, ar2, 1024); LDA(6, ar2, 2048); LDA(7, ar2, 3072);
#undef LDA
    asm volatile("s_waitcnt vmcnt(0)" ::: "memory");
    __builtin_amdgcn_sched_barrier(0);

    // 3. MFMA over this wave's 32 kc slices
    f32x4 acc[4];
    acc[0] = acc[1] = acc[2] = acc[3] = (f32x4){0.f, 0.f, 0.f, 0.f};
    #pragma unroll
    for (int i = 0; i < 8; ++i) {
      short8 a = __builtin_bit_cast(short8, fa[i]);
      acc[0] = __builtin_amdgcn_mfma_f32_16x16x32_bf16(
          a, *(const short8*)(bW + i * 2048 + 0),   acc[0], 0, 0, 0);
      acc[1] = __builtin_amdgcn_mfma_f32_16x16x32_bf16(
          a, *(const short8*)(bW + i * 2048 + 128), acc[1], 0, 0, 0);
      acc[2] = __builtin_amdgcn_mfma_f32_16x16x32_bf16(
          a, *(const short8*)(bW + i * 2048 + 256), acc[2], 0, 0, 0);
      acc[3] = __builtin_amdgcn_mfma_f32_16x16x32_bf16(
          a, *(const short8*)(bW + i * 2048 + 384), acc[3], 0, 0, 0);
    }

    // 4. publish K-partials: D row = lg*4+jj (batch), col = nt*16+lr
    float* pw = Pr + w * 1088;
    #pragma unroll
    for (int nt = 0; nt < 4; ++nt) {
      #pragma unroll
      for (int jj = 0; jj < 4; ++jj)
        pw[(lg * 4 + jj) * 68 + nt * 16 + lr] = acc[nt][jj];
    }
    __syncthreads();

    // 5. reduce 4 K-partials + sigmoid update (xpv, hpv carried in regs)
    const float* pb = Pr + brow * 68 + c0;
    f32x4 s = *(const f32x4*)(pb)
            + *(const f32x4*)(pb + 1088)
            + *(const f32x4*)(pb + 2176)
            + *(const f32x4*)(pb + 3264);
    f32x4 hn;
    #pragma unroll
    for (int k = 0; k < 4; ++k) {
      float pre = s[k] + xpv[k];
      float sg = 1.f / (1.f + __expf(-pre));
      hn[k] = 0.8f * hpv[k] + 0.2f * sg;  // 1-ALPHA, ALPHA, GAIN=1
    }

    // 6. publish h_{t+1} to the ring (one 8B relaxed-agent store per thread)
    {
      ull u = (ull)(unsigned short)f2bf(hn[0])
            | ((ull)(unsigned short)f2bf(hn[1]) << 16)
            | ((ull)(unsigned short)f2bf(hn[2]) << 32)
            | ((ull)(unsigned short)f2bf(hn[3]) << 48);
      __hip_atomic_store((ull*)(rn + ringoff), u,
                         __ATOMIC_RELAXED, __HIP_MEMORY_SCOPE_AGENT);
    }
    // 7. drain ring stores, block barrier (also Pr reuse guard), raise flag
    asm volatile("s_waitcnt vmcnt(0)" ::: "memory");
    __syncthreads();
    if (tid == 0)
      __hip_atomic_store(&flags[bid], t + 2, __ATOMIC_RELAXED, __HIP_MEMORY_SCOPE_AGENT);

    // 8. non-critical tail (hidden behind other blocks' consumption):
    //    write h_{t+1} to out, prefetch next x_proj, carry hn in register
    *(float4*)(outt + oidx) = *(float4*)&hn;
    if (t == TT - 1) {
      *(float4*)(out + (size_t)TT * BB * HH + oidx) = *(float4*)&hn;
    } else {
      float4 v = *(const float4*)(outt + BB * HH + oidx);
      xpv[0] = v.x; xpv[1] = v.y; xpv[2] = v.z; xpv[3] = v.w;
    }
    hpv = hn;
  }
}

extern "C" void kernel_launch(void* const* d_in, const int* in_sizes, int n_in,
                              void* d_out, int out_size, void* d_ws, size_t ws_size,
                              hipStream_t stream) {
  const float* x   = (const float*)d_in[0];
  const float* h0  = (const float*)d_in[1];
  const float* Win = (const float*)d_in[2];
  const float* bin = (const float*)d_in[3];
  const float* Whh = (const float*)d_in[4];
  const float* bhh = (const float*)d_in[5];
  float* out = (float*)d_out;

  int* flags = (int*)d_ws;                       // 64 ints (256 B)
  short* ring0 = (short*)((char*)d_ws + 256);    // 128 KB
  short* ring1 = ring0 + BB * HH;                // 128 KB (total 262,400 B, proven)

  hipMemsetAsync(d_ws, 0, 256, stream);
  xproj_kernel<<<dim3(TT), 256, 0, stream>>>(x, Win, bin, bhh, out);
  rnn_persist<<<dim3(64), 256, 0, stream>>>(h0, Whh, out, ring0, ring1, flags);
}